// Round 1
// baseline (73.945 us; speedup 1.0000x reference)
//
#include <hip/hip_runtime.h>

constexpr int D = 20;

__global__ __launch_bounds__(256) void cevae_rows_kernel(
    const float* __restrict__ x, const float* __restrict__ t,
    const float* __restrict__ y, const float* __restrict__ qz_w,
    const float* __restrict__ qz_b,
    const float* __restrict__ sc_tw, const float* __restrict__ sc_tb,
    const float* __restrict__ sc_y0w, const float* __restrict__ sc_y0b,
    const float* __restrict__ sc_y1w, const float* __restrict__ sc_y1b,
    const float* __restrict__ pz, float* __restrict__ out, int n_rows)
{
    int n = blockIdx.x * 256 + threadIdx.x;
    if (n >= n_rows) return;

    // x row: 20 floats = 5 aligned float4 (row stride 80 B, 16B-aligned)
    const float4* xr = (const float4*)(x + (size_t)n * D);
    float4 a = xr[0];
    float4 b = xr[1];
    float4 c = xr[2];
    float4 d = xr[3];
    float4 e = xr[4];
    float tv = t[n];
    float yv = y[n];

    // idx = t*2^20 + sum_j x_j * 2^(19-j)  (x values are exactly 0.0f/1.0f)
    unsigned idx = (tv != 0.0f) ? (1u << 20) : 0u;
    idx |= ((unsigned)a.x) << 19;
    idx |= ((unsigned)a.y) << 18;
    idx |= ((unsigned)a.z) << 17;
    idx |= ((unsigned)a.w) << 16;
    idx |= ((unsigned)b.x) << 15;
    idx |= ((unsigned)b.y) << 14;
    idx |= ((unsigned)b.z) << 13;
    idx |= ((unsigned)b.w) << 12;
    idx |= ((unsigned)c.x) << 11;
    idx |= ((unsigned)c.y) << 10;
    idx |= ((unsigned)c.z) << 9;
    idx |= ((unsigned)c.w) << 8;
    idx |= ((unsigned)d.x) << 7;
    idx |= ((unsigned)d.y) << 6;
    idx |= ((unsigned)d.z) << 5;
    idx |= ((unsigned)d.w) << 4;
    idx |= ((unsigned)e.x) << 3;
    idx |= ((unsigned)e.y) << 2;
    idx |= ((unsigned)e.z) << 1;
    idx |= ((unsigned)e.w);

    // z_logits
    float z = fmaf(qz_w[idx], yv, qz_b[idx]);
    out[n] = z;

    // scalar heads (uniform-address loads -> s_load, broadcast)
    float tw  = *sc_tw,  tb  = *sc_tb;
    float y0w = *sc_y0w, y0b = *sc_y0b;
    float y1w = *sc_y1w, y1b = *sc_y1b;

    // layout: [z(N)][xl0(N*D)][xl1(N*D)][t0(N)][t1(N)][y0(N)][y1(N)][pz(1)]
    size_t o3 = (size_t)n_rows * (size_t)(1 + 2 * D);
    out[o3 + n] = tb;                               // t_logits0 (z=0)
    out[o3 + (size_t)n_rows + n] = tw + tb;         // t_logits1 (z=1)
    // y_logits = (z*y1w+y1b)*t + (z*y0w+y0b)*(1-t)
    out[o3 + 2 * (size_t)n_rows + n] = fmaf(tv, y1b - y0b, y0b);                        // z=0
    out[o3 + 3 * (size_t)n_rows + n] = fmaf(tv, (y1w + y1b) - (y0w + y0b), y0w + y0b);  // z=1
    if (n == 0) out[o3 + 4 * (size_t)n_rows] = pz[0];   // pz_logit
}

// x_logits0[:, c] = dx_b[c]; x_logits1[:, c] = dx_w[c] + dx_b[c].
// Row-independent -> pure coalesced float4 fill. Pattern period = 5 float4s.
__global__ __launch_bounds__(256) void cevae_fill_kernel(
    const float* __restrict__ dx_w, const float* __restrict__ dx_b,
    float* __restrict__ out, int n_rows)
{
    size_t Q = (size_t)n_rows * D / 4;          // float4 count per region
    float4* r0 = (float4*)(out + n_rows);       // x_logits0
    float4* r1 = r0 + Q;                        // x_logits1
    size_t stride = (size_t)gridDim.x * blockDim.x;
    for (size_t q = (size_t)blockIdx.x * blockDim.x + threadIdx.x; q < Q; q += stride) {
        int cb = (int)(q % 5) * 4;              // column base 0,4,8,12,16
        float b0 = dx_b[cb + 0], b1 = dx_b[cb + 1], b2 = dx_b[cb + 2], b3 = dx_b[cb + 3];
        float w0 = dx_w[cb + 0], w1 = dx_w[cb + 1], w2 = dx_w[cb + 2], w3 = dx_w[cb + 3];
        r0[q] = make_float4(b0, b1, b2, b3);
        r1[q] = make_float4(w0 + b0, w1 + b1, w2 + b2, w3 + b3);
    }
}

extern "C" void kernel_launch(void* const* d_in, const int* in_sizes, int n_in,
                              void* d_out, int out_size, void* d_ws, size_t ws_size,
                              hipStream_t stream) {
    const float* x    = (const float*)d_in[0];
    const float* t    = (const float*)d_in[1];
    const float* y    = (const float*)d_in[2];
    const float* qz_w = (const float*)d_in[3];
    const float* qz_b = (const float*)d_in[4];
    const float* dx_w = (const float*)d_in[5];
    const float* dx_b = (const float*)d_in[6];
    const float* t_w  = (const float*)d_in[7];
    const float* t_b  = (const float*)d_in[8];
    const float* y0_w = (const float*)d_in[9];
    const float* y0_b = (const float*)d_in[10];
    const float* y1_w = (const float*)d_in[11];
    const float* y1_b = (const float*)d_in[12];
    const float* pz   = (const float*)d_in[13];
    float* out = (float*)d_out;

    int n_rows = in_sizes[0] / D;   // 1,000,000

    int blocks_rows = (n_rows + 255) / 256;
    cevae_rows_kernel<<<blocks_rows, 256, 0, stream>>>(
        x, t, y, qz_w, qz_b, t_w, t_b, y0_w, y0_b, y1_w, y1_b, pz, out, n_rows);

    cevae_fill_kernel<<<4096, 256, 0, stream>>>(dx_w, dx_b, out, n_rows);
}